// Round 1
// baseline (45.426 us; speedup 1.0000x reference)
//
#include <hip/hip_runtime.h>
#include <math.h>

#define N_ROWS 4096
#define D_DIM 128
#define K_CLS 512
#define EPS 1e-6f

// One block per row n. 256 threads, each handles k and k+256.
__global__ __launch_bounds__(256) void proto_scores_kernel(
    const float* __restrict__ x,      // (N, D)
    const int*   __restrict__ label,  // (N,)
    const float* __restrict__ w,      // (D, K)
    float* __restrict__ scores,       // (N, K)
    float* __restrict__ row_loss)     // (N,)
{
    const int n   = blockIdx.x;
    const int tid = threadIdx.x;

    __shared__ float xs[D_DIM];
    __shared__ float sc[K_CLS];
    __shared__ float redmax[4];
    __shared__ float redsum[4];

    if (tid < D_DIM) xs[tid] = x[n * D_DIM + tid];
    __syncthreads();

    const int k0 = tid;
    const int k1 = tid + 256;

    float acc0 = 0.f, acc1 = 0.f;
#pragma unroll 8
    for (int d = 0; d < D_DIM; ++d) {
        // (x - w + eps)^2 ; fold eps into x once per d
        const float xe = xs[d] + EPS;
        const float w0 = w[d * K_CLS + k0];
        const float w1 = w[d * K_CLS + k1];
        const float t0 = xe - w0;
        const float t1 = xe - w1;
        acc0 = fmaf(t0, t0, acc0);
        acc1 = fmaf(t1, t1, acc1);
    }

    const float s0 = -sqrtf(acc0);
    const float s1 = -sqrtf(acc1);

    scores[n * K_CLS + k0] = s0;
    scores[n * K_CLS + k1] = s1;
    sc[k0] = s0;
    sc[k1] = s1;

    // ---- block max over 512 scores (wave shuffle + LDS across 4 waves) ----
    float m = fmaxf(s0, s1);
#pragma unroll
    for (int off = 32; off >= 1; off >>= 1)
        m = fmaxf(m, __shfl_xor(m, off));
    if ((tid & 63) == 0) redmax[tid >> 6] = m;
    __syncthreads();  // also covers sc[] writes
    m = fmaxf(fmaxf(redmax[0], redmax[1]), fmaxf(redmax[2], redmax[3]));

    // ---- block sum of exp(s - m) ----
    float e = expf(s0 - m) + expf(s1 - m);
#pragma unroll
    for (int off = 32; off >= 1; off >>= 1)
        e += __shfl_xor(e, off);
    if ((tid & 63) == 0) redsum[tid >> 6] = e;
    __syncthreads();

    if (tid == 0) {
        const float sum = redsum[0] + redsum[1] + redsum[2] + redsum[3];
        const int lab = label[n];
        // -log_softmax at the label column
        row_loss[n] = -(sc[lab] - m - logf(sum));
    }
}

// Deterministic single-block reduction of per-row losses -> mean.
__global__ __launch_bounds__(256) void loss_reduce_kernel(
    const float* __restrict__ row_loss, float* __restrict__ out)
{
    __shared__ float red[4];
    const int tid = threadIdx.x;
    float s = 0.f;
    for (int i = tid; i < N_ROWS; i += 256) s += row_loss[i];
#pragma unroll
    for (int off = 32; off >= 1; off >>= 1)
        s += __shfl_xor(s, off);
    if ((tid & 63) == 0) red[tid >> 6] = s;
    __syncthreads();
    if (tid == 0)
        out[0] = (red[0] + red[1] + red[2] + red[3]) * (1.0f / N_ROWS);
}

extern "C" void kernel_launch(void* const* d_in, const int* in_sizes, int n_in,
                              void* d_out, int out_size, void* d_ws, size_t ws_size,
                              hipStream_t stream)
{
    const float* x     = (const float*)d_in[0];
    const int*   label = (const int*)d_in[1];
    const float* w     = (const float*)d_in[2];

    float* scores   = (float*)d_out;                 // N*K floats
    float* loss_out = (float*)d_out + (size_t)N_ROWS * K_CLS;  // 1 float
    float* row_loss = (float*)d_ws;                  // N floats scratch

    proto_scores_kernel<<<N_ROWS, 256, 0, stream>>>(x, label, w, scores, row_loss);
    loss_reduce_kernel<<<1, 256, 0, stream>>>(row_loss, loss_out);
}

// Round 2
// 26.910 us; speedup vs baseline: 1.6881x; 1.6881x over previous
//
#include <hip/hip_runtime.h>
#include <math.h>

#define N_ROWS 4096
#define D_DIM  128
#define K_CLS  512
#define TN     16
#define EPS    1e-6f

// One block = TN rows x all 512 classes. 256 threads, each owns k = 2*tid, 2*tid+1.
// dist^2(r,k) = sum_d (x+eps)^2  - 2*(sum_d x*w + eps*sum_d w) + sum_d w^2
//            =  sxs[r]           - 2*(acc[r][j] + eps*aw1[j])  + aw2[j]
__global__ __launch_bounds__(256) void proto_fused_kernel(
    const float* __restrict__ x,      // (N, D)
    const int*   __restrict__ label,  // (N,)
    const float* __restrict__ w,      // (D, K)
    float* __restrict__ scores,       // (N, K)
    float* __restrict__ row_loss)     // (N,)
{
    const int tid = threadIdx.x;
    const int n0  = blockIdx.x * TN;

    __shared__ float xs_t[D_DIM][TN];   // 8 KB  : x tile, transposed [d][row]
    __shared__ float sxs[TN];           // per-row sum (x+eps)^2
    __shared__ float sc[TN][K_CLS];     // 32 KB : score tile for softmax/loss
    __shared__ float wred[4][TN];       // cross-wave partials

    // ---- stage x tile transposed: thread t -> row t&15, d-chunk (t>>4)*8 ----
    {
        const int row   = tid & 15;
        const int dbase = (tid >> 4) * 8;
        const float4 a = *(const float4*)&x[(size_t)(n0 + row) * D_DIM + dbase];
        const float4 b = *(const float4*)&x[(size_t)(n0 + row) * D_DIM + dbase + 4];
        xs_t[dbase + 0][row] = a.x;
        xs_t[dbase + 1][row] = a.y;
        xs_t[dbase + 2][row] = a.z;
        xs_t[dbase + 3][row] = a.w;
        xs_t[dbase + 4][row] = b.x;
        xs_t[dbase + 5][row] = b.y;
        xs_t[dbase + 6][row] = b.z;
        xs_t[dbase + 7][row] = b.w;
    }
    __syncthreads();

    // ---- per-row sum of (x+eps)^2 ----
    {
        const int row = tid & 15;
        const int g   = tid >> 4;                 // 16 d-chunks
        float p = 0.f;
#pragma unroll
        for (int i = 0; i < 8; ++i) {
            const float v = xs_t[g * 8 + i][row] + EPS;
            p = fmaf(v, v, p);
        }
        // same-row partials sit at lanes l, l+16, l+32, l+48 within each wave
        p += __shfl_xor(p, 16);
        p += __shfl_xor(p, 32);
        if ((tid & 63) < TN) wred[tid >> 6][tid & 15] = p;
    }
    __syncthreads();
    if (tid < TN)
        sxs[tid] = wred[0][tid] + wred[1][tid] + wred[2][tid] + wred[3][tid];
    __syncthreads();

    // ---- main loop: acc[r][j] = sum_d x[r][d] * w[d][k_j]; aw1/aw2 on the fly ----
    float acc[TN][2];
#pragma unroll
    for (int r = 0; r < TN; ++r) { acc[r][0] = 0.f; acc[r][1] = 0.f; }
    float aw1[2] = {0.f, 0.f}, aw2[2] = {0.f, 0.f};

    const float2* __restrict__ w2 = (const float2*)w;  // k = 2*tid, 2*tid+1
#pragma unroll 4
    for (int d = 0; d < D_DIM; ++d) {
        const float2 wv = w2[d * (K_CLS / 2) + tid];
        aw1[0] += wv.x;
        aw1[1] += wv.y;
        aw2[0] = fmaf(wv.x, wv.x, aw2[0]);
        aw2[1] = fmaf(wv.y, wv.y, aw2[1]);
        const float4 xa = *(const float4*)&xs_t[d][0];
        const float4 xb = *(const float4*)&xs_t[d][4];
        const float4 xc = *(const float4*)&xs_t[d][8];
        const float4 xd = *(const float4*)&xs_t[d][12];
#define FMA2(r, xv)                                  \
        acc[r][0] = fmaf((xv), wv.x, acc[r][0]);     \
        acc[r][1] = fmaf((xv), wv.y, acc[r][1]);
        FMA2(0,  xa.x) FMA2(1,  xa.y) FMA2(2,  xa.z) FMA2(3,  xa.w)
        FMA2(4,  xb.x) FMA2(5,  xb.y) FMA2(6,  xb.z) FMA2(7,  xb.w)
        FMA2(8,  xc.x) FMA2(9,  xc.y) FMA2(10, xc.z) FMA2(11, xc.w)
        FMA2(12, xd.x) FMA2(13, xd.y) FMA2(14, xd.z) FMA2(15, xd.w)
#undef FMA2
    }

    // ---- epilogue: scores + LDS score tile ----
    const int k0 = tid * 2;
#pragma unroll
    for (int r = 0; r < TN; ++r) {
        const float d0 = sxs[r] - 2.f * fmaf(EPS, aw1[0], acc[r][0]) + aw2[0];
        const float d1 = sxs[r] - 2.f * fmaf(EPS, aw1[1], acc[r][1]) + aw2[1];
        const float s0 = -sqrtf(d0);
        const float s1 = -sqrtf(d1);
        const float2 sv = make_float2(s0, s1);
        *(float2*)&scores[(size_t)(n0 + r) * K_CLS + k0] = sv;
        *(float2*)&sc[r][k0] = sv;
    }
    __syncthreads();

    // ---- softmax + per-row loss: wave handles rows wave, wave+4, wave+8, wave+12 ----
    const int wave = tid >> 6;
    const int lane = tid & 63;
#pragma unroll
    for (int rr = 0; rr < 4; ++rr) {
        const int r = wave + rr * 4;
        float v[8];
#pragma unroll
        for (int i = 0; i < 8; ++i) v[i] = sc[r][lane + 64 * i];
        float m = v[0];
#pragma unroll
        for (int i = 1; i < 8; ++i) m = fmaxf(m, v[i]);
#pragma unroll
        for (int off = 32; off >= 1; off >>= 1) m = fmaxf(m, __shfl_xor(m, off));
        float e = 0.f;
#pragma unroll
        for (int i = 0; i < 8; ++i) e += expf(v[i] - m);
#pragma unroll
        for (int off = 32; off >= 1; off >>= 1) e += __shfl_xor(e, off);
        if (lane == 0) {
            const int lab = label[n0 + r];
            row_loss[n0 + r] = -(sc[r][lab] - m - logf(e));
        }
    }
}

// Deterministic single-block reduction of per-row losses -> mean.
__global__ __launch_bounds__(256) void loss_reduce_kernel(
    const float* __restrict__ row_loss, float* __restrict__ out)
{
    __shared__ float red[4];
    const int tid = threadIdx.x;
    float s = 0.f;
    for (int i = tid; i < N_ROWS; i += 256) s += row_loss[i];
#pragma unroll
    for (int off = 32; off >= 1; off >>= 1) s += __shfl_xor(s, off);
    if ((tid & 63) == 0) red[tid >> 6] = s;
    __syncthreads();
    if (tid == 0)
        out[0] = (red[0] + red[1] + red[2] + red[3]) * (1.0f / N_ROWS);
}

extern "C" void kernel_launch(void* const* d_in, const int* in_sizes, int n_in,
                              void* d_out, int out_size, void* d_ws, size_t ws_size,
                              hipStream_t stream)
{
    const float* x     = (const float*)d_in[0];
    const int*   label = (const int*)d_in[1];
    const float* w     = (const float*)d_in[2];

    float* scores   = (float*)d_out;                           // N*K floats
    float* loss_out = (float*)d_out + (size_t)N_ROWS * K_CLS;  // 1 float
    float* row_loss = (float*)d_ws;                            // N floats scratch

    proto_fused_kernel<<<N_ROWS / TN, 256, 0, stream>>>(x, label, w, scores, row_loss);
    loss_reduce_kernel<<<1, 256, 0, stream>>>(row_loss, loss_out);
}